// Round 17
// baseline (303.895 us; speedup 1.0000x reference)
//
#include <hip/hip_runtime.h>
#include <math.h>

// Problem dims (fixed)
#define B_   128
#define L_   256
#define H_   128
#define H2_  256
#define VS_  256

__device__ __forceinline__ float fma4(float4 a, float4 b, float acc) {
    acc = fmaf(a.x, b.x, acc);
    acc = fmaf(a.y, b.y, acc);
    acc = fmaf(a.z, b.z, acc);
    acc = fmaf(a.w, b.w, acc);
    return acc;
}

template <int CTRL>
__device__ __forceinline__ float dpp_add(float x) {
    int y = __builtin_amdgcn_update_dpp(0, __float_as_int(x), CTRL, 0xf, 0xf, true);
    return x + __int_as_float(y);
}
// Full 64-lane sum; total lands in lane 63.
__device__ __forceinline__ float wave_sum(float x) {
    x = dpp_add<0x111>(x);  // row_shr:1
    x = dpp_add<0x112>(x);  // row_shr:2
    x = dpp_add<0x114>(x);  // row_shr:4
    x = dpp_add<0x118>(x);  // row_shr:8
    x = dpp_add<0x142>(x);  // row_bcast:15
    x = dpp_add<0x143>(x);  // row_bcast:31
    return x;
}

// ---------------------------------------------------------------------------
// Kernel 1: per-VOCAB fused FFN + per-vocab scan tables (unchanged, verified).
// ---------------------------------------------------------------------------
__global__ __launch_bounds__(256) void k_vffn(
    const float* __restrict__ embed,
    const float* __restrict__ W1, const float* __restrict__ b1,
    const float* __restrict__ W2, const float* __restrict__ b2,
    const float* __restrict__ gamma, const float* __restrict__ beta,
    const float* __restrict__ Wk, float* __restrict__ Fout,
    float* __restrict__ n2g, float* __restrict__ rnag, float* __restrict__ thrg)
{
    __shared__ float sh_h[4][128];
    __shared__ float sh_y[4][256];

    const int tid  = threadIdx.x;
    const int lane = tid & 63;
    const int r    = tid >> 6;
    const int v    = blockIdx.x * 4 + r;

    const float4* embed4 = (const float4*)embed;
    const float4* W1_4   = (const float4*)W1;
    const float4* W2_4   = (const float4*)W2;
    const float4* Wk_4   = (const float4*)Wk;

    if (lane < 32)
        *(float4*)&sh_h[r][lane * 4] = embed4[v * 32 + lane];
    __syncthreads();

    #pragma unroll
    for (int jj = 0; jj < 4; ++jj) {
        int j = jj * 64 + lane;
        const float4* wrow = W1_4 + j * 32;
        float acc = 0.f;
        #pragma unroll
        for (int c4 = 0; c4 < 32; ++c4)
            acc = fma4(*(const float4*)&sh_h[r][c4 * 4], wrow[c4], acc);
        sh_y[r][j] = fmaxf(acc + b1[j], 0.f);
    }
    __syncthreads();

    float xv[4];
    #pragma unroll
    for (int cc = 0; cc < 4; ++cc) {
        int c  = cc * 32 + (lane & 31);
        int hf = lane >> 5;
        const float4* wrow = W2_4 + c * 64 + hf * 32;
        float acc = 0.f;
        #pragma unroll
        for (int j4 = 0; j4 < 32; ++j4)
            acc = fma4(*(const float4*)&sh_y[r][(hf * 32 + j4) * 4], wrow[j4], acc);
        acc += __shfl_xor(acc, 32);
        xv[cc] = acc;
    }
    if (lane < 32) {
        #pragma unroll
        for (int cc = 0; cc < 4; ++cc) {
            int c = cc * 32 + lane;
            sh_h[r][c] = sh_h[r][c] + xv[cc] + b2[c];
        }
    }
    __syncthreads();

    {
        float2 x2 = *(const float2*)&sh_h[r][lane * 2];
        float s  = x2.x + x2.y;
        float s2 = x2.x * x2.x + x2.y * x2.y;
        s  += __shfl_xor(s, 1);  s  += __shfl_xor(s, 2);  s  += __shfl_xor(s, 4);
        s  += __shfl_xor(s, 8);  s  += __shfl_xor(s, 16); s  += __shfl_xor(s, 32);
        s2 += __shfl_xor(s2, 1); s2 += __shfl_xor(s2, 2); s2 += __shfl_xor(s2, 4);
        s2 += __shfl_xor(s2, 8); s2 += __shfl_xor(s2, 16); s2 += __shfl_xor(s2, 32);
        float mu   = s * (1.f / 128.f);
        float var  = s2 * (1.f / 128.f) - mu * mu;
        float rstd = 1.f / sqrtf(var + 1e-5f);
        float2 g2  = *(const float2*)&gamma[lane * 2];
        float2 be2 = *(const float2*)&beta[lane * 2];
        float2 o;
        o.x = (x2.x - mu) * rstd * g2.x + be2.x;
        o.y = (x2.y - mu) * rstd * g2.y + be2.y;
        *(float2*)&sh_h[r][lane * 2] = o;
    }
    __syncthreads();

    float fk0, fk1;
    {
        int k0 = lane, k1 = 64 + lane;
        const float4* w0 = Wk_4 + k0 * 32;
        const float4* w1 = Wk_4 + k1 * 32;
        float a0 = 0.f, a1 = 0.f;
        #pragma unroll
        for (int c4 = 0; c4 < 32; ++c4) {
            float4 h4 = *(const float4*)&sh_h[r][c4 * 4];
            a0 = fma4(h4, w0[c4], a0);
            a1 = fma4(h4, w1[c4], a1);
        }
        Fout[v * 128 + lane]      = a0;
        Fout[v * 128 + 64 + lane] = a1;
        fk0 = a0; fk1 = a1;
    }
    {
        float n2 = fmaf(fk0, fk0, fk1 * fk1);
        n2 += __shfl_xor(n2, 1);  n2 += __shfl_xor(n2, 2);  n2 += __shfl_xor(n2, 4);
        n2 += __shfl_xor(n2, 8);  n2 += __shfl_xor(n2, 16); n2 += __shfl_xor(n2, 32);
        if (lane == 0) {
            n2g[v]  = n2;
            rnag[v] = 1.f / fmaxf(sqrtf(n2), 1e-12f);
            thrg[v] = 0.16f * n2;
        }
    }
}

// ---------------------------------------------------------------------------
// Kernel 2: gated delta-rule scan — deferred-update decoupling (R16 algebra,
//   exact) with the two measured costs fixed:
//   (a) 5-slot VMEM kb ring (KM 2-region lead, KU 5-region) + 5-slot kself
//       ring (4-region lead) — L2 latency off the chain;
//   (b) LDS insts/step/wave ~4.5: one tbl float4 broadcast (carried +1),
//       one part4 b128 read, one b32 part write, red b64; wave_sum cc==0 only.
//   Per-step chain: part/red read -> gate -> pre(3 fmaf) -> errN -> wave_sum
//   -> red write -> barrier. Update(m,KU)+matvec(m,KM) are gate-independent.
// ---------------------------------------------------------------------------
__global__ __launch_bounds__(512, 2) void k_scan(
    const int* __restrict__ seq, const float* __restrict__ Fbuf,
    const float* __restrict__ n2g, const float* __restrict__ rnag,
    const float* __restrict__ thrg,
    const float* __restrict__ Wr, const float* __restrict__ br,
    const float* __restrict__ Wo, const float* __restrict__ bo,
    float* __restrict__ out)
{
    __shared__ float4 part4_[2][128];    // [parity][row] = {p_cc0..p_cc3}
    __shared__ float  red_[2][2];        // [parity][row-half]
    __shared__ float4 tbl4_[256];        // {rna[t], thr[t], d01[t], d2[t]}
    __shared__ int    seqb_[256];

    const int tid  = threadIdx.x;
    const int lane = tid & 63;
    const int w    = tid >> 6;
    const int cc   = w & 3;
    const int rh   = w >> 2;
    const int row  = rh * 64 + lane;
    const int b    = blockIdx.x;
    const float4* F4 = (const float4*)Fbuf;

    // ---- prologue ----
    if (tid < 256) seqb_[tid] = seq[b * 256 + tid];
    __syncthreads();

    if (tid < 256) {
        int v = seqb_[tid];
        tbl4_[tid].x = rnag[v];
        tbl4_[tid].y = thrg[v];
        if (tid == 0) { tbl4_[0].w = 0.f; tbl4_[255].z = 0.f; }
    } else if (tid < 511) {
        int t = tid - 256;                       // 0..254
        int tn  = t + 1;
        int tn2 = (t + 2 > 255) ? 255 : t + 2;
        int va = seqb_[t], vb = seqb_[tn], vc = seqb_[tn2];
        const float4* A  = F4 + va * 32;
        const float4* Bp = F4 + vb * 32;
        const float4* Cp = F4 + vc * 32;
        float a0 = 0.f, a1 = 0.f, c0 = 0.f, c1 = 0.f;
        #pragma unroll
        for (int u = 0; u < 16; ++u) {
            a0 = fma4(A[u],      Bp[u],      a0);
            a1 = fma4(A[16 + u], Bp[16 + u], a1);
            c0 = fma4(A[u],      Cp[u],      c0);
            c1 = fma4(A[16 + u], Cp[16 + u], c1);
        }
        tbl4_[t].z = a0 + a1;                    // d01[t] = k_t . k_{t+1}
        if (t + 1 <= 255) tbl4_[t + 1].w = c0 + c1;  // d2[t+1] = k_t . k_{t+2}
    }
    part4_[0][tid & 127] = make_float4(0.f, 0.f, 0.f, 0.f);
    if (tid == 0) red_[0][1] = 0.f;
    if (tid == 1) red_[0][0] = n2g[seqb_[0]];    // e2_0 = ||k_0||^2

    // per-lane / per-wave register init
    float errT = Fbuf[(size_t)seqb_[0] * 128 + row];   // err_0 = k_0[row]
    float errP = 0.f, avP = 0.f;
    float ks0 = 0.f, ks1, ks2, ks3, ks4;
    ks1 = Fbuf[(size_t)seqb_[1] * 128 + row];
    ks2 = Fbuf[(size_t)seqb_[2] * 128 + row];
    ks3 = Fbuf[(size_t)seqb_[3] * 128 + row];
    ks4 = Fbuf[(size_t)seqb_[4] * 128 + row];
    float4 m[8], kb0[8], kb1[8], kb2[8], kb3[8], kb4[8];
    {
        int v0 = seqb_[0], v1 = seqb_[1], v2 = seqb_[2], v3 = seqb_[3];
        #pragma unroll
        for (int u = 0; u < 8; ++u) {
            m[u]   = make_float4(0.f, 0.f, 0.f, 0.f);
            kb0[u] = make_float4(0.f, 0.f, 0.f, 0.f);  // "k_{-1}" (x avP=0)
            kb1[u] = F4[(size_t)v0 * 32 + cc * 8 + u]; // k_0
            kb2[u] = F4[(size_t)v1 * 32 + cc * 8 + u]; // k_1
            kb3[u] = F4[(size_t)v2 * 32 + cc * 8 + u]; // k_2
            kb4[u] = F4[(size_t)v3 * 32 + cc * 8 + u]; // k_3
        }
    }
    __syncthreads();

    // carried per-step scalars (registers)
    float4 t0v = tbl4_[0], t1v = tbl4_[1];
    float rnaC = t0v.x, thrC = t0v.y, d01C = t0v.z, d2C = t0v.w;
    float4 tblN = t1v;                           // tbl[t+1]

// REG(T): KU holds k_{T-1} (update operand; refilled <- k_{T+4});
//         KM holds k_{T+2} (matvec operand, 2-region lead);
//         KSU = kself_{T+1}; KSF refilled <- kself_{T+5} (4-region lead).
#define REG(T, KU, KM, KSU, KSF)                                                \
  {                                                                             \
    const int t_ = (T), pr = t_ & 1, pw = pr ^ 1;                               \
    float4 tblN2 = tbl4_[(t_ + 2 > 255) ? 255 : t_ + 2];                        \
    int sv4 = seqb_[(t_ + 4 > 255) ? 255 : t_ + 4];                             \
    int sv5 = seqb_[(t_ + 5 > 255) ? 255 : t_ + 5];                             \
    /* gate-independent: deferred update (scale fixed last region) + matvec */  \
    float sc = avP * errP;                                                      \
    if (avP != 0.f) {                            /* uniform branch */           \
      _Pragma("unroll")                                                         \
      for (int u = 0; u < 8; ++u) {              /* m -> M_{t-1} */             \
        m[u].x = fmaf(sc, KU[u].x, m[u].x);                                     \
        m[u].y = fmaf(sc, KU[u].y, m[u].y);                                     \
        m[u].z = fmaf(sc, KU[u].z, m[u].z);                                     \
        m[u].w = fmaf(sc, KU[u].w, m[u].w);                                     \
      }                                                                         \
    }                                                                           \
    float q0 = 0.f, q1 = 0.f, q2 = 0.f, q3 = 0.f;                               \
    q0 = fma4(m[0], KM[0], q0); q1 = fma4(m[1], KM[1], q1);                     \
    q2 = fma4(m[2], KM[2], q2); q3 = fma4(m[3], KM[3], q3);                     \
    q0 = fma4(m[4], KM[4], q0); q1 = fma4(m[5], KM[5], q1);                     \
    q2 = fma4(m[6], KM[6], q2); q3 = fma4(m[7], KM[7], q3);                     \
    /* short chain */                                                           \
    float4 pv = part4_[pr][row];                                                \
    float E2 = red_[pr][0] + red_[pr][1];                                       \
    float praw = (pv.x + pv.y) + (pv.z + pv.w); /* M_{t-2} . k_{t+1} */         \
    float av = (E2 >= thrC) ? rnaC : 0.f;                                       \
    float pre = fmaf(av * errT, d01C, fmaf(sc, d2C, praw));                     \
    float errN = fmaf(-tblN.x, pre, KSU);       /* err_{t+1} */                 \
    if (cc == 0) {                                                              \
      float e2p = wave_sum(errN * errN);                                        \
      if (lane == 63) red_[pw][rh] = e2p;                                       \
    }                                                                           \
    ((float*)&part4_[pw][row])[cc] = (q0 + q1) + (q2 + q3);                     \
    /* VMEM refills (stay in flight across the barrier) */                      \
    KSF = Fbuf[(size_t)sv5 * 128 + row];                                        \
    _Pragma("unroll")                                                           \
    for (int u = 0; u < 8; ++u)                                                 \
      KU[u] = F4[(size_t)sv4 * 32 + cc * 8 + u];                                \
    __builtin_amdgcn_sched_barrier(0);                                          \
    asm volatile("s_waitcnt lgkmcnt(0)" ::: "memory");                          \
    __builtin_amdgcn_sched_barrier(0);                                          \
    __builtin_amdgcn_s_barrier();                                               \
    __builtin_amdgcn_sched_barrier(0);                                          \
    errP = errT; avP = av; errT = errN;                                         \
    rnaC = tblN.x; thrC = tblN.y; d01C = tblN.z; d2C = tblN.w;                  \
    tblN = tblN2;                                                               \
  }

    // Regions 0..249 (period-5 ring rotation), then 250..253 explicit.
    for (int tt = 0; tt < 250; tt += 5) {
        REG(tt + 0, kb0, kb3, ks1, ks0);
        REG(tt + 1, kb1, kb4, ks2, ks1);
        REG(tt + 2, kb2, kb0, ks3, ks2);
        REG(tt + 3, kb3, kb1, ks4, ks3);
        REG(tt + 4, kb4, kb2, ks0, ks4);
    }
    REG(250, kb0, kb3, ks1, ks0);
    REG(251, kb1, kb4, ks2, ks1);
    REG(252, kb2, kb0, ks3, ks2);
    REG(253, kb3, kb1, ks4, ks3);
#undef REG

    // ---- epilogue t=254: pre = M_254·k_255 = readout[row] ----
    float* rd_ = (float*)&part4_[1][0];     // parity-1 not read below
    float* r2_ = (float*)&tbl4_[0];         // tbl values already in regs
    {
        float4 pv = part4_[0][row];                  // M_252 . k_255
        float E2 = red_[0][0] + red_[0][1];
        float praw = (pv.x + pv.y) + (pv.z + pv.w);
        float av = (E2 >= thrC) ? rnaC : 0.f;        // thr/rna[254]
        float sc = avP * errP;
        float pre = fmaf(av * errT, d01C, fmaf(sc, d2C, praw));
        if (cc == 0) rd_[row] = pre;                 // M_254·k_255
    }
    __syncthreads();

    // ---- fused out-projection: out = (rd @ Wr^T + br) @ Wo^T + bo ----
    {
        int i = tid >> 2, q = tid & 3;
        const float4* Wr4 = (const float4*)Wr;
        const float4* rdv = (const float4*)rd_;
        float s = 0.f;
        #pragma unroll
        for (int u = 0; u < 8; ++u) s = fma4(rdv[q * 8 + u], Wr4[i * 32 + q * 8 + u], s);
        s += __shfl_xor(s, 1);
        s += __shfl_xor(s, 2);
        if (q == 0) r2_[i] = s + br[i];
    }
    __syncthreads();
    {
        int v = tid >> 1, h = tid & 1;
        const float4* Wo4 = (const float4*)Wo;
        const float4* r2v = (const float4*)r2_;
        float s = 0.f;
        #pragma unroll
        for (int u = 0; u < 16; ++u) s = fma4(r2v[h * 16 + u], Wo4[v * 32 + h * 16 + u], s);
        s += __shfl_xor(s, 1);
        if (h == 0) out[b * 256 + v] = s + bo[v];
    }
}

// ---------------------------------------------------------------------------
extern "C" void kernel_launch(void* const* d_in, const int* in_sizes, int n_in,
                              void* d_out, int out_size, void* d_ws, size_t ws_size,
                              hipStream_t stream) {
    const int*   seq   = (const int*)  d_in[0];
    const float* embed = (const float*)d_in[1];
    const float* W1    = (const float*)d_in[2];
    const float* b1    = (const float*)d_in[3];
    const float* W2    = (const float*)d_in[4];
    const float* b2    = (const float*)d_in[5];
    const float* gamma = (const float*)d_in[6];
    const float* beta  = (const float*)d_in[7];
    const float* Wk    = (const float*)d_in[8];
    const float* Wr    = (const float*)d_in[9];
    const float* br    = (const float*)d_in[10];
    const float* Wo    = (const float*)d_in[11];
    const float* bo    = (const float*)d_in[12];

    float* Fbuf = (float*)d_ws;                      // 256*128 f32 = 128 KiB
    float* n2g  = Fbuf + VS_ * H_;                   // 256
    float* rnag = n2g + VS_;                         // 256
    float* thrg = rnag + VS_;                        // 256
    float* out  = (float*)d_out;

    k_vffn<<<VS_ / 4, 256, 0, stream>>>(embed, W1, b1, W2, b2, gamma, beta, Wk,
                                        Fbuf, n2g, rnag, thrg);
    k_scan<<<B_, 512, 0, stream>>>(seq, Fbuf, n2g, rnag, thrg,
                                   Wr, br, Wo, bo, out);
}

// Round 18
// 158.605 us; speedup vs baseline: 1.9161x; 1.9161x over previous
//
#include <hip/hip_runtime.h>
#include <math.h>

// Problem dims (fixed)
#define B_   128
#define L_   256
#define H_   128
#define H2_  256
#define VS_  256

__device__ __forceinline__ float fma4(float4 a, float4 b, float acc) {
    acc = fmaf(a.x, b.x, acc);
    acc = fmaf(a.y, b.y, acc);
    acc = fmaf(a.z, b.z, acc);
    acc = fmaf(a.w, b.w, acc);
    return acc;
}

template <int CTRL>
__device__ __forceinline__ float dpp_add(float x) {
    int y = __builtin_amdgcn_update_dpp(0, __float_as_int(x), CTRL, 0xf, 0xf, true);
    return x + __int_as_float(y);
}
// Full 64-lane sum; total lands in lane 63.
__device__ __forceinline__ float wave_sum(float x) {
    x = dpp_add<0x111>(x);  // row_shr:1
    x = dpp_add<0x112>(x);  // row_shr:2
    x = dpp_add<0x114>(x);  // row_shr:4
    x = dpp_add<0x118>(x);  // row_shr:8
    x = dpp_add<0x142>(x);  // row_bcast:15
    x = dpp_add<0x143>(x);  // row_bcast:31
    return x;
}
// Sum over the 4 lanes of each quad (butterfly -> valid in all 4 lanes).
__device__ __forceinline__ float quad_sum(float x) {
    x = dpp_add<0xB1>(x);   // quad_perm [1,0,3,2]
    x = dpp_add<0x4E>(x);   // quad_perm [2,3,0,1]
    return x;
}

// ---------------------------------------------------------------------------
// Kernel 1: per-VOCAB fused FFN (R11, measured ~4 us).
//   F[v] = Wk( LN(embed[v]+FFN(embed[v])) ), F: 256 x 128.
// ---------------------------------------------------------------------------
__global__ __launch_bounds__(256) void k_vffn(
    const float* __restrict__ embed,
    const float* __restrict__ W1, const float* __restrict__ b1,
    const float* __restrict__ W2, const float* __restrict__ b2,
    const float* __restrict__ gamma, const float* __restrict__ beta,
    const float* __restrict__ Wk, float* __restrict__ Fout)
{
    __shared__ float sh_h[4][128];
    __shared__ float sh_y[4][256];

    const int tid  = threadIdx.x;
    const int lane = tid & 63;
    const int r    = tid >> 6;
    const int v    = blockIdx.x * 4 + r;

    const float4* embed4 = (const float4*)embed;
    const float4* W1_4   = (const float4*)W1;
    const float4* W2_4   = (const float4*)W2;
    const float4* Wk_4   = (const float4*)Wk;

    if (lane < 32)
        *(float4*)&sh_h[r][lane * 4] = embed4[v * 32 + lane];
    __syncthreads();

    #pragma unroll
    for (int jj = 0; jj < 4; ++jj) {
        int j = jj * 64 + lane;
        const float4* wrow = W1_4 + j * 32;
        float acc = 0.f;
        #pragma unroll
        for (int c4 = 0; c4 < 32; ++c4)
            acc = fma4(*(const float4*)&sh_h[r][c4 * 4], wrow[c4], acc);
        sh_y[r][j] = fmaxf(acc + b1[j], 0.f);
    }
    __syncthreads();

    float xv[4];
    #pragma unroll
    for (int cc = 0; cc < 4; ++cc) {
        int c  = cc * 32 + (lane & 31);
        int hf = lane >> 5;
        const float4* wrow = W2_4 + c * 64 + hf * 32;
        float acc = 0.f;
        #pragma unroll
        for (int j4 = 0; j4 < 32; ++j4)
            acc = fma4(*(const float4*)&sh_y[r][(hf * 32 + j4) * 4], wrow[j4], acc);
        acc += __shfl_xor(acc, 32);
        xv[cc] = acc;
    }
    if (lane < 32) {
        #pragma unroll
        for (int cc = 0; cc < 4; ++cc) {
            int c = cc * 32 + lane;
            sh_h[r][c] = sh_h[r][c] + xv[cc] + b2[c];
        }
    }
    __syncthreads();

    {
        float2 x2 = *(const float2*)&sh_h[r][lane * 2];
        float s  = x2.x + x2.y;
        float s2 = x2.x * x2.x + x2.y * x2.y;
        s  += __shfl_xor(s, 1);  s  += __shfl_xor(s, 2);  s  += __shfl_xor(s, 4);
        s  += __shfl_xor(s, 8);  s  += __shfl_xor(s, 16); s  += __shfl_xor(s, 32);
        s2 += __shfl_xor(s2, 1); s2 += __shfl_xor(s2, 2); s2 += __shfl_xor(s2, 4);
        s2 += __shfl_xor(s2, 8); s2 += __shfl_xor(s2, 16); s2 += __shfl_xor(s2, 32);
        float mu   = s * (1.f / 128.f);
        float var  = s2 * (1.f / 128.f) - mu * mu;
        float rstd = 1.f / sqrtf(var + 1e-5f);
        float2 g2  = *(const float2*)&gamma[lane * 2];
        float2 be2 = *(const float2*)&beta[lane * 2];
        float2 o;
        o.x = (x2.x - mu) * rstd * g2.x + be2.x;
        o.y = (x2.y - mu) * rstd * g2.y + be2.y;
        *(float2*)&sh_h[r][lane * 2] = o;
    }
    __syncthreads();

    #pragma unroll
    for (int kk = 0; kk < 2; ++kk) {
        int k = kk * 64 + lane;
        const float4* wrow = Wk_4 + k * 32;
        float acc = 0.f;
        #pragma unroll
        for (int c4 = 0; c4 < 32; ++c4)
            acc = fma4(*(const float4*)&sh_h[r][c4 * 4], wrow[c4], acc);
        Fout[v * 128 + k] = acc;
    }
}

// ---------------------------------------------------------------------------
// Kernel 2: gated delta-rule scan — EXACT R11 main loop (measured 122 us):
//   LDS k-store gathered from F via seq; gate-decoupled matvec
//   (pre = M_{t-1}k_{t+1} + a*d01[t], exact); counted-lgkmcnt raw barrier
//   (refill ds_reads stay in flight); 4-stage DPP e2 reduce.
//   ONLY change vs R11: out-projection fused into the epilogue
//   (readout never leaves the block; k_out launch removed).
// ---------------------------------------------------------------------------
__global__ __launch_bounds__(512) void k_scan(
    const int* __restrict__ seq, const float* __restrict__ Fbuf,
    const float* __restrict__ Wr, const float* __restrict__ br,
    const float* __restrict__ Wo, const float* __restrict__ bo,
    float* __restrict__ out)
{
    extern __shared__ float smem_f[];
    float4* shk4  = (float4*)smem_f;          // [256][32] float4 = 128 KiB
    float*  shkf  = smem_f;                   // same, scalar view
    float*  rna   = smem_f + 32768;           // [256] 1/max(||k_t||,eps)
    float*  thr   = rna + 256;                // [256] 0.16*||k_t||^2
    float*  d01   = thr + 256;                // [256] k_t . k_{t+1} (raw)
    float*  red_f = d01 + 256;                // [2][8] e2 partials
    float*  rd_   = red_f + 16;               // [128] readout
    float*  r2_   = rd_ + 128;                // [128] hidden of out-proj

    const int tid  = threadIdx.x;
    const int lane = tid & 63;
    const int w    = tid >> 6;        // wave id 0..7
    const int cq   = lane & 3;        // col chunk 0..3 (32 cols each)
    const int row  = w * 16 + (lane >> 2);   // 0..127
    const int b    = blockIdx.x;
    const float4* F4 = (const float4*)Fbuf;
    const int* seqb = seq + b * 256;

    // ---- prologue 1: gather all 256 k vectors from F via seq ----
    for (int f = tid; f < 8192; f += 512) {
        int t = f >> 5, c = f & 31;
        shk4[f] = F4[(size_t)seqb[t] * 32 + c];
    }
    __syncthreads();

    // ---- prologue 2: per-row norms + neighbor dots ----
    {
        int rr = tid >> 4, cc = tid & 15;
        for (int it = 0; it < 8; ++it) {
            int t  = it * 32 + rr;
            int tn = (t < 255) ? t + 1 : 255;
            float4 a0 = shk4[t  * 32 + cc], a1 = shk4[t  * 32 + 16 + cc];
            float4 b0 = shk4[tn * 32 + cc], b1 = shk4[tn * 32 + 16 + cc];
            float n2p = fma4(a1, a1, fma4(a0, a0, 0.f));
            float cp  = fma4(a1, b1, fma4(a0, b0, 0.f));
            n2p += __shfl_xor(n2p, 1); n2p += __shfl_xor(n2p, 2);
            n2p += __shfl_xor(n2p, 4); n2p += __shfl_xor(n2p, 8);
            cp  += __shfl_xor(cp, 1);  cp  += __shfl_xor(cp, 2);
            cp  += __shfl_xor(cp, 4);  cp  += __shfl_xor(cp, 8);
            if (cc == 0) {
                rna[t] = 1.f / fmaxf(sqrtf(n2p), 1e-12f);
                thr[t] = 0.16f * n2p;
                d01[t] = cp;
            }
        }
    }

    // ---- M row slice, k buffers, err_0 ----
    float4 m[8];
    #pragma unroll
    for (int u = 0; u < 8; ++u) m[u] = make_float4(0.f, 0.f, 0.f, 0.f);

    float4 kbE[8], kbO[8];
    {
        const float4* ks0 = shk4 + cq * 8;
        const float4* ks1 = shk4 + 32 + cq * 8;
        #pragma unroll
        for (int u = 0; u < 8; ++u) {
            kbE[u] = ks0[(u + cq) & 7];   // k_0
            kbO[u] = ks1[(u + cq) & 7];   // k_1
        }
    }
    float errR = shkf[row];               // err_0 = k_0[row]
    {
        float e2p = (cq == 0) ? errR * errR : 0.f;
        e2p = wave_sum(e2p);
        if (lane == 63) red_f[w] = e2p;   // parity-0 slots for region 0
    }
    __syncthreads();

#define REGION(T, KU, KM)                                                       \
  {                                                                             \
    const int t_ = (T);                                                         \
    float rnaT = rna[t_], rnaN = rna[t_ + 1];                                   \
    float thrT = thr[t_], d01T = d01[t_];                                       \
    float kselfN = shkf[(t_ + 1) * 128 + row];                                  \
    float4 ra = ((const float4*)red_f)[(t_ & 1) * 2];                           \
    float4 rb = ((const float4*)red_f)[(t_ & 1) * 2 + 1];                       \
    /* gate-independent matvec with M_{t-1}, overlaps the red read */           \
    float pA = 0.f, pB = 0.f;                                                   \
    pA = fma4(m[0], KM[0], pA); pB = fma4(m[1], KM[1], pB);                     \
    pA = fma4(m[2], KM[2], pA); pB = fma4(m[3], KM[3], pB);                     \
    pA = fma4(m[4], KM[4], pA); pB = fma4(m[5], KM[5], pB);                     \
    pA = fma4(m[6], KM[6], pA); pB = fma4(m[7], KM[7], pB);                     \
    float preM = quad_sum(pA + pB);                                             \
    float E2 = ((ra.x + ra.y) + (ra.z + ra.w)) +                                \
               ((rb.x + rb.y) + (rb.z + rb.w));                                 \
    float a_ = (E2 >= thrT) ? rnaT * errR : 0.f;                                \
    float pre = fmaf(a_, d01T, preM);    /* = M_t · k_{t+1}, exact */           \
    float errN = fmaf(-rnaN, pre, kselfN);                                      \
    /* errN is quad-uniform -> 4-stage reduce picks one lane per quad */        \
    float e2p = errN * errN;                                                    \
    e2p = dpp_add<0x114>(e2p);   /* row_shr:4  */                               \
    e2p = dpp_add<0x118>(e2p);   /* row_shr:8  */                               \
    e2p = dpp_add<0x142>(e2p);   /* row_bcast:15 */                             \
    e2p = dpp_add<0x143>(e2p);   /* row_bcast:31 -> lane63 total */             \
    if (lane == 63) red_f[((t_ + 1) & 1) * 8 + w] = e2p;                        \
    __builtin_amdgcn_sched_barrier(0);                                          \
    /* deferred update + refill: issued AFTER the red write (in-order DS) */    \
    _Pragma("unroll")                                                           \
    for (int u = 0; u < 8; ++u) {                                               \
      m[u].x = fmaf(a_, KU[u].x, m[u].x);                                       \
      m[u].y = fmaf(a_, KU[u].y, m[u].y);                                       \
      m[u].z = fmaf(a_, KU[u].z, m[u].z);                                       \
      m[u].w = fmaf(a_, KU[u].w, m[u].w);                                       \
    }                                                                           \
    {                                                                           \
      const float4* ks = shk4 + (t_ + 2) * 32 + cq * 8;                         \
      _Pragma("unroll")                                                         \
      for (int u = 0; u < 8; ++u) KU[u] = ks[(u + cq) & 7];                     \
    }                                                                           \
    __builtin_amdgcn_sched_barrier(0);                                          \
    /* write(1)+reads(8)=9 outstanding; lgkmcnt(8) retires the write only —    \
       the refill reads stay in flight ACROSS the barrier */                    \
    asm volatile("s_waitcnt lgkmcnt(8)" ::: "memory");                          \
    __builtin_amdgcn_sched_barrier(0);                                          \
    __builtin_amdgcn_s_barrier();                                               \
    errR = errN;                                                                \
  }

    // Regions 0..253: after region t, m = M_t, errR = err_{t+1}.
    for (int tt = 0; tt < 254; tt += 2) {
        REGION(tt,     kbE, kbO);
        REGION(tt + 1, kbO, kbE);
    }
#undef REGION

    // ---- epilogue: step 254 fused into readout -> LDS rd_ ----
    {
        float4 ra = ((const float4*)red_f)[0];   // parity (254&1)=0 slots
        float4 rb = ((const float4*)red_f)[1];
        float E2 = ((ra.x + ra.y) + (ra.z + ra.w)) +
                   ((rb.x + rb.y) + (rb.z + rb.w));
        float a_ = (E2 >= thr[254]) ? rna[254] * errR : 0.f;
        float pA = 0.f, pB = 0.f;
        pA = fma4(m[0], kbO[0], pA); pB = fma4(m[1], kbO[1], pB);
        pA = fma4(m[2], kbO[2], pA); pB = fma4(m[3], kbO[3], pB);
        pA = fma4(m[4], kbO[4], pA); pB = fma4(m[5], kbO[5], pB);
        pA = fma4(m[6], kbO[6], pA); pB = fma4(m[7], kbO[7], pB);
        float preM = quad_sum(pA + pB);
        float pre  = fmaf(a_, d01[254], preM);   // M_254 · k_255 = readout
        if (cq == 0) rd_[row] = pre;
    }
    __syncthreads();

    // ---- fused out-projection: out = (rd @ Wr^T + br) @ Wo^T + bo ----
    {
        int i = tid >> 2, q = tid & 3;           // 4 threads per hidden elem
        const float4* Wr4 = (const float4*)Wr;
        const float4* rdv = (const float4*)rd_;
        float s = 0.f;
        #pragma unroll
        for (int u = 0; u < 8; ++u) s = fma4(rdv[q * 8 + u], Wr4[i * 32 + q * 8 + u], s);
        s += __shfl_xor(s, 1);
        s += __shfl_xor(s, 2);
        if (q == 0) r2_[i] = s + br[i];
    }
    __syncthreads();
    {
        int v = tid >> 1, h = tid & 1;           // 2 threads per output elem
        const float4* Wo4 = (const float4*)Wo;
        const float4* r2v = (const float4*)r2_;
        float s = 0.f;
        #pragma unroll
        for (int u = 0; u < 16; ++u) s = fma4(r2v[h * 16 + u], Wo4[v * 32 + h * 16 + u], s);
        s += __shfl_xor(s, 1);
        if (h == 0) out[b * 256 + v] = s + bo[v];
    }
}

// ---------------------------------------------------------------------------
extern "C" void kernel_launch(void* const* d_in, const int* in_sizes, int n_in,
                              void* d_out, int out_size, void* d_ws, size_t ws_size,
                              hipStream_t stream) {
    const int*   seq   = (const int*)  d_in[0];
    const float* embed = (const float*)d_in[1];
    const float* W1    = (const float*)d_in[2];
    const float* b1    = (const float*)d_in[3];
    const float* W2    = (const float*)d_in[4];
    const float* b2    = (const float*)d_in[5];
    const float* gamma = (const float*)d_in[6];
    const float* beta  = (const float*)d_in[7];
    const float* Wk    = (const float*)d_in[8];
    const float* Wr    = (const float*)d_in[9];
    const float* br    = (const float*)d_in[10];
    const float* Wo    = (const float*)d_in[11];
    const float* bo    = (const float*)d_in[12];

    float* Fbuf = (float*)d_ws;                      // 256*128 f32 = 128 KiB
    float* out  = (float*)d_out;

    // k_scan dynamic LDS: 128 KiB k-store + rna/thr/d01 + red + rd + r2
    const size_t scan_lds = 32768 * 4 + 3 * 256 * 4 + 16 * 4 + 2 * 128 * 4;

    k_vffn<<<VS_ / 4, 256, 0, stream>>>(embed, W1, b1, W2, b2, gamma, beta, Wk, Fbuf);
    k_scan<<<B_, 512, scan_lds, stream>>>(seq, Fbuf, Wr, br, Wo, bo, out);
}